// Round 2
// baseline (654.030 us; speedup 1.0000x reference)
//
#include <hip/hip_runtime.h>
#include <hip/hip_bf16.h>
#include <math.h>

#define HID   128
#define TPB   256      // 4 waves per block
#define WROWS 32       // rows per wave (2 row-tiles of 16)
#define TROWS 128      // rows per block-tile
#define NBLK  768      // persistent grid (~3 blocks/CU)

typedef __attribute__((ext_vector_type(8))) short        short8v;   // 8 bf16
typedef __attribute__((ext_vector_type(4))) float        f32x4;
typedef __attribute__((ext_vector_type(4))) unsigned int uint4v;

__device__ __forceinline__ unsigned int pk2bf(float lo, float hi) {
    unsigned short a = __builtin_bit_cast(unsigned short, __float2bfloat16(lo));
    unsigned short b = __builtin_bit_cast(unsigned short, __float2bfloat16(hi));
    return (unsigned int)a | ((unsigned int)b << 16);
}

__global__ __launch_bounds__(TPB, 3)
void stress_kernel(const float* __restrict__ F,
                   const float* __restrict__ W1, const float* __restrict__ b1,
                   const float* __restrict__ W2, const float* __restrict__ b2,
                   const float* __restrict__ W3, const float* __restrict__ b3,
                   float* __restrict__ out, int N)
{
    // ---- LDS: constant, fragment-ordered weights (46 KB -> 3 blocks/CU) ----
    __shared__ uint4v sA2[2048];   // 32 KB  W2^T A-frags: [(jt*4+ks)*64 + lane]
    __shared__ uint4v sA3[256];    //  4 KB  W3^T A-frags: [ks2*64 + lane]
    __shared__ f32x4  sB2f[512];   //  8 KB  b2 in D2-fragment order: [jt*64 + lane]
    __shared__ float  sW1[3 * HID];
    __shared__ float  sb1[HID];

    const int tid  = threadIdx.x;
    const int lane = tid & 63;
    const int wid  = tid >> 6;
    const int g    = lane >> 4;     // lane group 0..3
    const int lr   = lane & 15;

    // ---- one-time per-block weight staging / swizzling ----
    // A2: value(lane,b,ks,jt) = bf16( W2[k][j] ), k = 8g+b+32ks, j = lr+16jt
    for (int e = tid; e < 2048; e += TPB) {
        int l = e & 63, ks = (e >> 6) & 3, jt = e >> 8;
        int k0 = 8 * (l >> 4) + 32 * ks;
        int j  = (l & 15) + 16 * jt;
        uint4v v;
        v.x = pk2bf(W2[(k0 + 0) * HID + j], W2[(k0 + 1) * HID + j]);
        v.y = pk2bf(W2[(k0 + 2) * HID + j], W2[(k0 + 3) * HID + j]);
        v.z = pk2bf(W2[(k0 + 4) * HID + j], W2[(k0 + 5) * HID + j]);
        v.w = pk2bf(W2[(k0 + 6) * HID + j], W2[(k0 + 7) * HID + j]);
        sA2[e] = v;
    }
    // A3: row t = lr (pad t>=4 with 0), slot (g,b,ks2) -> j = 4g+(b&3)+16*(2ks2+(b>>2))
    for (int e = tid; e < 256; e += TPB) {
        int l = e & 63, ks2 = e >> 6;
        int gg = l >> 4, t = l & 15;
        float w[8];
        #pragma unroll
        for (int b = 0; b < 8; ++b) {
            int j = 4 * gg + (b & 3) + 16 * (2 * ks2 + (b >> 2));
            w[b] = (t < 4) ? W3[j * 4 + t] : 0.f;
        }
        uint4v v;
        v.x = pk2bf(w[0], w[1]); v.y = pk2bf(w[2], w[3]);
        v.z = pk2bf(w[4], w[5]); v.w = pk2bf(w[6], w[7]);
        sA3[e] = v;
    }
    // b2 in D2 fragment order: reg r of lane l, tile jt -> b2[4g + r + 16jt]
    for (int e = tid; e < 512; e += TPB) {
        int l = e & 63, jt = e >> 6;
        int base = 4 * (l >> 4) + 16 * jt;
        f32x4 v;
        v.x = b2[base + 0]; v.y = b2[base + 1];
        v.z = b2[base + 2]; v.w = b2[base + 3];
        sB2f[e] = v;
    }
    for (int i = tid; i < 3 * HID; i += TPB) sW1[i] = W1[i];
    for (int i = tid; i < HID; i += TPB)     sb1[i] = b1[i];
    __syncthreads();

    // preload W3^T fragments into registers (constant across tiles)
    short8v a3f[4];
    #pragma unroll
    for (int ks2 = 0; ks2 < 4; ++ks2)
        a3f[ks2] = __builtin_bit_cast(short8v, sA3[ks2 * 64 + lane]);

    const int nTiles = (N + TROWS - 1) / TROWS;
    for (int tile = blockIdx.x; tile < nTiles; tile += gridDim.x) {
        const int wbase = tile * TROWS + wid * WROWS;

        // ---- invariants: lanes 0..31 own rows wbase+lane ----
        float x0 = 0.f, x1 = 0.f, x2 = 0.f;
        if (lane < 32) {
            int n = wbase + lane;
            float a = 0.f, b = 0.f, c = 0.f, d = 0.f;
            if (n < N) {
                f32x4 f = ((const f32x4*)F)[n];
                a = f.x; b = f.y; c = f.z; d = f.w;
            }
            float J  = a * d - b * c;
            float ss = a * a + b * b + c * c + d * d;
            float r  = sqrtf(fmaxf(ss + 2.f * fabsf(J), 1e-30f));
            x0 = r - 2.f; x1 = ss - 1.f; x2 = J - 1.f;
        }
        // broadcast x of row (rt*16 + lr) to all lanes
        float xa[2][3];
        #pragma unroll
        for (int rt = 0; rt < 2; ++rt) {
            int src = rt * 16 + lr;
            xa[rt][0] = __shfl(x0, src, 64);
            xa[rt][1] = __shfl(x1, src, 64);
            xa[rt][2] = __shfl(x2, src, 64);
        }

        // ---- layer 2: h2^T = W2^T * h1^T  (h1 built on the fly in regs) ----
        f32x4 acc[2][8];
        #pragma unroll
        for (int rt = 0; rt < 2; ++rt)
            #pragma unroll
            for (int jt = 0; jt < 8; ++jt)
                acc[rt][jt] = (f32x4){0.f, 0.f, 0.f, 0.f};

        #pragma unroll
        for (int ks = 0; ks < 4; ++ks) {
            const int k0 = 8 * g + 32 * ks;
            float w1v[3][8], b1v[8];
            #pragma unroll
            for (int i = 0; i < 3; ++i) {
                *(f32x4*)&w1v[i][0] = *(const f32x4*)&sW1[i * HID + k0];
                *(f32x4*)&w1v[i][4] = *(const f32x4*)&sW1[i * HID + k0 + 4];
            }
            *(f32x4*)&b1v[0] = *(const f32x4*)&sb1[k0];
            *(f32x4*)&b1v[4] = *(const f32x4*)&sb1[k0 + 4];

            short8v bfrag[2];
            #pragma unroll
            for (int rt = 0; rt < 2; ++rt) {
                float h[8];
                #pragma unroll
                for (int b = 0; b < 8; ++b)
                    h[b] = fmaxf(b1v[b] + xa[rt][0] * w1v[0][b]
                                        + xa[rt][1] * w1v[1][b]
                                        + xa[rt][2] * w1v[2][b], 0.f);
                uint4v u;
                u.x = pk2bf(h[0], h[1]); u.y = pk2bf(h[2], h[3]);
                u.z = pk2bf(h[4], h[5]); u.w = pk2bf(h[6], h[7]);
                bfrag[rt] = __builtin_bit_cast(short8v, u);
            }
            #pragma unroll
            for (int jt = 0; jt < 8; ++jt) {
                short8v af = __builtin_bit_cast(short8v, sA2[(jt * 4 + ks) * 64 + lane]);
                acc[0][jt] = __builtin_amdgcn_mfma_f32_16x16x32_bf16(af, bfrag[0], acc[0][jt], 0, 0, 0);
                acc[1][jt] = __builtin_amdgcn_mfma_f32_16x16x32_bf16(af, bfrag[1], acc[1][jt], 0, 0, 0);
            }
        }

        // ---- layer 3 (MFMA, W3^T padded) + epilogue ----
        #pragma unroll
        for (int rt = 0; rt < 2; ++rt) {
            f32x4 accY = (f32x4){0.f, 0.f, 0.f, 0.f};
            #pragma unroll
            for (int ks2 = 0; ks2 < 4; ++ks2) {
                f32x4 ba = sB2f[(2 * ks2) * 64 + lane];
                f32x4 bb = sB2f[(2 * ks2 + 1) * 64 + lane];
                f32x4 ha, hb;
                ha.x = fmaxf(acc[rt][2 * ks2].x + ba.x, 0.f);
                ha.y = fmaxf(acc[rt][2 * ks2].y + ba.y, 0.f);
                ha.z = fmaxf(acc[rt][2 * ks2].z + ba.z, 0.f);
                ha.w = fmaxf(acc[rt][2 * ks2].w + ba.w, 0.f);
                hb.x = fmaxf(acc[rt][2 * ks2 + 1].x + bb.x, 0.f);
                hb.y = fmaxf(acc[rt][2 * ks2 + 1].y + bb.y, 0.f);
                hb.z = fmaxf(acc[rt][2 * ks2 + 1].z + bb.z, 0.f);
                hb.w = fmaxf(acc[rt][2 * ks2 + 1].w + bb.w, 0.f);
                uint4v u;
                u.x = pk2bf(ha.x, ha.y); u.y = pk2bf(ha.z, ha.w);
                u.z = pk2bf(hb.x, hb.y); u.w = pk2bf(hb.z, hb.w);
                short8v b3f = __builtin_bit_cast(short8v, u);
                accY = __builtin_amdgcn_mfma_f32_16x16x32_bf16(a3f[ks2], b3f, accY, 0, 0, 0);
            }
            // lanes 0..15 hold y[0..3] of row wbase + rt*16 + lane
            if (lane < 16) {
                int n = wbase + rt * 16 + lane;
                if (n < N) {
                    f32x4 fv = ((const f32x4*)F)[n];
                    float a = fv.x, b = fv.y, c = fv.z, d = fv.w;
                    float J   = a * d - b * c;
                    float ss  = a * a + b * b + c * c + d * d;
                    float sgn = (J >= 0.f) ? 1.f : -1.f;
                    float inv = 1.f / sqrtf(fmaxf(ss + 2.f * fabsf(J), 1e-30f));
                    float R00 = (a + sgn * d) * inv, R01 = (b - sgn * c) * inv;
                    float R10 = (c - sgn * b) * inv, R11 = (d + sgn * a) * inv;
                    float y0 = accY.x, y1 = accY.y, y2 = accY.z, y3 = accY.w;
                    float s01 = 0.5f * (y1 + y2);
                    float P00 = R00 * y0  + R01 * s01;
                    float P01 = R00 * s01 + R01 * y3;
                    float P10 = R10 * y0  + R11 * s01;
                    float P11 = R10 * s01 + R11 * y3;
                    f32x4 o;
                    o.x = P00 * a + P01 * b;   // cauchy = P @ F^T
                    o.y = P00 * c + P01 * d;
                    o.z = P10 * a + P11 * b;
                    o.w = P10 * c + P11 * d;
                    ((f32x4*)out)[n] = o;
                }
            }
        }
    }
}

extern "C" void kernel_launch(void* const* d_in, const int* in_sizes, int n_in,
                              void* d_out, int out_size, void* d_ws, size_t ws_size,
                              hipStream_t stream) {
    const float* F  = (const float*)d_in[0];
    const float* W1 = (const float*)d_in[1];
    const float* b1 = (const float*)d_in[2];
    const float* W2 = (const float*)d_in[3];
    const float* b2 = (const float*)d_in[4];
    const float* W3 = (const float*)d_in[5];
    const float* b3 = (const float*)d_in[6];
    float* out = (float*)d_out;
    const int N = in_sizes[0] / 4;

    const int nTiles = (N + TROWS - 1) / TROWS;
    int grid = nTiles < NBLK ? nTiles : NBLK;
    stress_kernel<<<dim3(grid), dim3(TPB), 0, stream>>>(F, W1, b1, W2, b2, W3, b3, out, N);
}

// Round 3
// 451.747 us; speedup vs baseline: 1.4478x; 1.4478x over previous
//
#include <hip/hip_runtime.h>
#include <hip/hip_bf16.h>
#include <math.h>

#define HID   128
#define TPB   256      // 4 waves per block
#define TROWS 128      // rows per block-tile (32 per wave)
#define NBLK  768      // persistent grid (~3 blocks/CU)

typedef __attribute__((ext_vector_type(8))) short        short8v;   // 8 bf16
typedef __attribute__((ext_vector_type(4))) float        f32x4;
typedef __attribute__((ext_vector_type(4))) unsigned int uint4v;

#define MFMA(a, b, c) __builtin_amdgcn_mfma_f32_16x16x32_bf16((a), (b), (c), 0, 0, 0)

__device__ __forceinline__ unsigned int pk2bf(float lo, float hi) {
    unsigned short a = __builtin_bit_cast(unsigned short, __float2bfloat16(lo));
    unsigned short b = __builtin_bit_cast(unsigned short, __float2bfloat16(hi));
    return (unsigned int)a | ((unsigned int)b << 16);
}
__device__ __forceinline__ f32x4 relu4(f32x4 v) {
    f32x4 r;
    r.x = fmaxf(v.x, 0.f); r.y = fmaxf(v.y, 0.f);
    r.z = fmaxf(v.z, 0.f); r.w = fmaxf(v.w, 0.f);
    return r;
}

__global__ __launch_bounds__(TPB, 3)
void stress_kernel(const float* __restrict__ F,
                   const float* __restrict__ W1, const float* __restrict__ b1,
                   const float* __restrict__ W2, const float* __restrict__ b2,
                   const float* __restrict__ W3, const float* __restrict__ b3,
                   float* __restrict__ out, int N)
{
    // ---- LDS: constant, fragment-ordered weights (46 KB -> 3 blocks/CU) ----
    __shared__ uint4v sA2[2048];   // 32 KB  W2^T A-frags: [(jt*4+ks)*64 + lane]
    __shared__ uint4v sA3[256];    //  4 KB  W3^T A-frags: [ks2*64 + lane]
    __shared__ f32x4  sB2f[512];   //  8 KB  b2 in D2-fragment order: [jt*64 + lane]
    __shared__ __align__(16) float sW1[3 * HID];
    __shared__ __align__(16) float sb1[HID];

    const int tid  = threadIdx.x;
    const int lane = tid & 63;
    const int wid  = tid >> 6;
    const int g    = lane >> 4;     // lane group 0..3
    const int lr   = lane & 15;

    // ---- one-time per-block weight staging / swizzling ----
    // A2: value(lane,b,ks,jt) = bf16( W2[k][j] ), k = 8g+b+32ks, j = lr+16jt
    for (int e = tid; e < 2048; e += TPB) {
        int l = e & 63, ks = (e >> 6) & 3, jt = e >> 8;
        int k0 = 8 * (l >> 4) + 32 * ks;
        int j  = (l & 15) + 16 * jt;
        uint4v v;
        v.x = pk2bf(W2[(k0 + 0) * HID + j], W2[(k0 + 1) * HID + j]);
        v.y = pk2bf(W2[(k0 + 2) * HID + j], W2[(k0 + 3) * HID + j]);
        v.z = pk2bf(W2[(k0 + 4) * HID + j], W2[(k0 + 5) * HID + j]);
        v.w = pk2bf(W2[(k0 + 6) * HID + j], W2[(k0 + 7) * HID + j]);
        sA2[e] = v;
    }
    // A3: row t = lr (pad t>=4 with 0), slot (g,b,ks2) -> j = 4g+(b&3)+16*(2ks2+(b>>2))
    for (int e = tid; e < 256; e += TPB) {
        int l = e & 63, ks2 = e >> 6;
        int gg = l >> 4, t = l & 15;
        float w0 = (t < 4) ? W3[(4 * gg + 0 + 16 * (2 * ks2 + 0)) * 4 + t] : 0.f;
        float w1_ = (t < 4) ? W3[(4 * gg + 1 + 16 * (2 * ks2 + 0)) * 4 + t] : 0.f;
        float w2_ = (t < 4) ? W3[(4 * gg + 2 + 16 * (2 * ks2 + 0)) * 4 + t] : 0.f;
        float w3_ = (t < 4) ? W3[(4 * gg + 3 + 16 * (2 * ks2 + 0)) * 4 + t] : 0.f;
        float w4 = (t < 4) ? W3[(4 * gg + 0 + 16 * (2 * ks2 + 1)) * 4 + t] : 0.f;
        float w5 = (t < 4) ? W3[(4 * gg + 1 + 16 * (2 * ks2 + 1)) * 4 + t] : 0.f;
        float w6 = (t < 4) ? W3[(4 * gg + 2 + 16 * (2 * ks2 + 1)) * 4 + t] : 0.f;
        float w7 = (t < 4) ? W3[(4 * gg + 3 + 16 * (2 * ks2 + 1)) * 4 + t] : 0.f;
        uint4v v;
        v.x = pk2bf(w0, w1_); v.y = pk2bf(w2_, w3_);
        v.z = pk2bf(w4, w5);  v.w = pk2bf(w6, w7);
        sA3[e] = v;
    }
    // b2 in D2 fragment order: reg r of lane l, tile jt -> b2[4g + r + 16jt]
    for (int e = tid; e < 512; e += TPB) {
        int l = e & 63, jt = e >> 6;
        int base = 4 * (l >> 4) + 16 * jt;
        f32x4 v;
        v.x = b2[base + 0]; v.y = b2[base + 1];
        v.z = b2[base + 2]; v.w = b2[base + 3];
        sB2f[e] = v;
    }
    for (int i = tid; i < 3 * HID; i += TPB) sW1[i] = W1[i];
    for (int i = tid; i < HID; i += TPB)     sb1[i] = b1[i];
    __syncthreads();

    // typed LDS views for clean vector reads (no scalar-array aliasing)
    const f32x4* pW1 = (const f32x4*)sW1;   // pW1[i*32 + k/4] = W1[i][k..k+3]
    const f32x4* pB1 = (const f32x4*)sb1;

    // preload W3^T fragments into registers (constant across tiles)
    short8v a3f[4];
    #pragma unroll
    for (int ks2 = 0; ks2 < 4; ++ks2)
        a3f[ks2] = __builtin_bit_cast(short8v, sA3[ks2 * 64 + lane]);

    const int nTiles = (N + TROWS - 1) / TROWS;
    for (int tile = blockIdx.x; tile < nTiles; tile += gridDim.x) {
        const int wbase = tile * TROWS + wid * 32;

        // ---- invariants: lanes 0..31 own rows wbase+lane ----
        float x0 = 0.f, x1 = 0.f, x2 = 0.f;
        if (lane < 32) {
            int n = wbase + lane;
            float a = 0.f, b = 0.f, c = 0.f, d = 0.f;
            if (n < N) {
                f32x4 f = ((const f32x4*)F)[n];
                a = f.x; b = f.y; c = f.z; d = f.w;
            }
            float J  = a * d - b * c;
            float ss = a * a + b * b + c * c + d * d;
            float r  = sqrtf(fmaxf(ss + 2.f * fabsf(J), 1e-30f));
            x0 = r - 2.f; x1 = ss - 1.f; x2 = J - 1.f;
        }
        // broadcast x of row (rt*16 + lr) to all lanes (named scalars only)
        const float xa00 = __shfl(x0, lr, 64);
        const float xa01 = __shfl(x1, lr, 64);
        const float xa02 = __shfl(x2, lr, 64);
        const float xa10 = __shfl(x0, 16 + lr, 64);
        const float xa11 = __shfl(x1, 16 + lr, 64);
        const float xa12 = __shfl(x2, 16 + lr, 64);

        // ---- layer 2: h2^T = W2^T * h1^T  (h1 built on the fly in regs) ----
        f32x4 acc0[8], acc1[8];
        #pragma unroll
        for (int jt = 0; jt < 8; ++jt) {
            acc0[jt] = (f32x4){0.f, 0.f, 0.f, 0.f};
            acc1[jt] = (f32x4){0.f, 0.f, 0.f, 0.f};
        }

        #pragma unroll
        for (int ks = 0; ks < 4; ++ks) {
            const int q = 2 * g + 8 * ks;        // f32x4 index of k0 = 8g+32ks
            const f32x4 w0lo = pW1[q],      w0hi = pW1[q + 1];        // W1[0][k0..]
            const f32x4 w1lo = pW1[32 + q], w1hi = pW1[32 + q + 1];   // W1[1][k0..]
            const f32x4 w2lo = pW1[64 + q], w2hi = pW1[64 + q + 1];   // W1[2][k0..]
            const f32x4 blo  = pB1[q],      bhi  = pB1[q + 1];

            const f32x4 h0lo = relu4(blo + w0lo * xa00 + w1lo * xa01 + w2lo * xa02);
            const f32x4 h0hi = relu4(bhi + w0hi * xa00 + w1hi * xa01 + w2hi * xa02);
            const f32x4 h1lo = relu4(blo + w0lo * xa10 + w1lo * xa11 + w2lo * xa12);
            const f32x4 h1hi = relu4(bhi + w0hi * xa10 + w1hi * xa11 + w2hi * xa12);

            uint4v u0, u1;
            u0.x = pk2bf(h0lo.x, h0lo.y); u0.y = pk2bf(h0lo.z, h0lo.w);
            u0.z = pk2bf(h0hi.x, h0hi.y); u0.w = pk2bf(h0hi.z, h0hi.w);
            u1.x = pk2bf(h1lo.x, h1lo.y); u1.y = pk2bf(h1lo.z, h1lo.w);
            u1.z = pk2bf(h1hi.x, h1hi.y); u1.w = pk2bf(h1hi.z, h1hi.w);
            const short8v bf0 = __builtin_bit_cast(short8v, u0);
            const short8v bf1 = __builtin_bit_cast(short8v, u1);

            #pragma unroll
            for (int jt = 0; jt < 8; ++jt) {
                const short8v af = __builtin_bit_cast(short8v, sA2[(jt * 4 + ks) * 64 + lane]);
                acc0[jt] = MFMA(af, bf0, acc0[jt]);
                acc1[jt] = MFMA(af, bf1, acc1[jt]);
            }
        }

        // ---- layer 3 (MFMA, W3^T padded) + epilogue ----
        #pragma unroll
        for (int rt = 0; rt < 2; ++rt) {
            f32x4 accY = (f32x4){0.f, 0.f, 0.f, 0.f};
            #pragma unroll
            for (int ks2 = 0; ks2 < 4; ++ks2) {
                const f32x4 ba = sB2f[(2 * ks2) * 64 + lane];
                const f32x4 bb = sB2f[(2 * ks2 + 1) * 64 + lane];
                const f32x4 ha = relu4((rt == 0 ? acc0[2 * ks2]     : acc1[2 * ks2])     + ba);
                const f32x4 hb = relu4((rt == 0 ? acc0[2 * ks2 + 1] : acc1[2 * ks2 + 1]) + bb);
                uint4v u;
                u.x = pk2bf(ha.x, ha.y); u.y = pk2bf(ha.z, ha.w);
                u.z = pk2bf(hb.x, hb.y); u.w = pk2bf(hb.z, hb.w);
                accY = MFMA(a3f[ks2], __builtin_bit_cast(short8v, u), accY);
            }
            // lanes 0..15 hold y[0..3] of row wbase + rt*16 + lane
            if (lane < 16) {
                int n = wbase + rt * 16 + lane;
                if (n < N) {
                    const f32x4 fv = ((const f32x4*)F)[n];
                    const float a = fv.x, b = fv.y, c = fv.z, d = fv.w;
                    const float J   = a * d - b * c;
                    const float ss  = a * a + b * b + c * c + d * d;
                    const float sgn = (J >= 0.f) ? 1.f : -1.f;
                    const float inv = 1.f / sqrtf(fmaxf(ss + 2.f * fabsf(J), 1e-30f));
                    const float R00 = (a + sgn * d) * inv, R01 = (b - sgn * c) * inv;
                    const float R10 = (c - sgn * b) * inv, R11 = (d + sgn * a) * inv;
                    const float y0 = accY.x, y1 = accY.y, y2 = accY.z, y3 = accY.w;
                    const float s01 = 0.5f * (y1 + y2);
                    const float P00 = R00 * y0  + R01 * s01;
                    const float P01 = R00 * s01 + R01 * y3;
                    const float P10 = R10 * y0  + R11 * s01;
                    const float P11 = R10 * s01 + R11 * y3;
                    f32x4 o;
                    o.x = P00 * a + P01 * b;   // cauchy = P @ F^T
                    o.y = P00 * c + P01 * d;
                    o.z = P10 * a + P11 * b;
                    o.w = P10 * c + P11 * d;
                    ((f32x4*)out)[n] = o;
                }
            }
        }
    }
}

extern "C" void kernel_launch(void* const* d_in, const int* in_sizes, int n_in,
                              void* d_out, int out_size, void* d_ws, size_t ws_size,
                              hipStream_t stream) {
    const float* F  = (const float*)d_in[0];
    const float* W1 = (const float*)d_in[1];
    const float* b1 = (const float*)d_in[2];
    const float* W2 = (const float*)d_in[3];
    const float* b2 = (const float*)d_in[4];
    const float* W3 = (const float*)d_in[5];
    const float* b3 = (const float*)d_in[6];
    float* out = (float*)d_out;
    const int N = in_sizes[0] / 4;

    const int nTiles = (N + TROWS - 1) / TROWS;
    int grid = nTiles < NBLK ? nTiles : NBLK;
    stress_kernel<<<dim3(grid), dim3(TPB), 0, stream>>>(F, W1, b1, W2, b2, W3, b3, out, N);
}